// Round 11
// baseline (2202.001 us; speedup 1.0000x reference)
//
#include <hip/hip_runtime.h>
#include <hip/hip_bf16.h>

#define NPTS 8192
#define KS   1024
#define NB   16

// ===========================================================================
// FPS: one block per batch, 1024 threads, 8 pts/thread.
// Coords explicitly parked in AGPRs (v_accvgpr_write/read) -- rounds 4/6
// showed the compiler refuses register residency (VGPR=40) and re-streams
// ~half the coords from L2 every step (~2000 cyc/step of the 3765 total).
// AGPR class is explicit: regalloc cannot sink or re-stream.
// Distance math: bit-exact vs jnp (sequential sub/mul/add, fp contract OFF).
// Reduce: value-only f32 max butterfly + ballot/ctz/readlane (first-
// occurrence tie-break preserved: lane order == index order at both levels).
// ONE barrier/step; parity-double-buffered per-wave results; centroid via
// SGPR-uniform scalar load from x.
// ===========================================================================
__global__ __launch_bounds__(1024, 4)
__attribute__((amdgpu_waves_per_eu(4, 4)))
void fps_kernel(const float* __restrict__ x, int* __restrict__ idx_out) {
#pragma clang fp contract(off)
  const int b    = blockIdx.x;
  const int tid  = threadIdx.x;
  const int lane = tid & 63;
  const int wave = tid >> 6;
  const float* xb = x + (size_t)b * NPTS * 6;

  // Load this thread's 8 consecutive points (48 floats = 12 float4) and
  // park them in AGPRs.
  float ca[48];
  {
    const float4* src = reinterpret_cast<const float4*>(xb + tid * 48);
    #pragma unroll
    for (int i = 0; i < 12; ++i) {
      float4 v = src[i];
      asm volatile("v_accvgpr_write_b32 %0, %1" : "=a"(ca[4*i+0]) : "v"(v.x));
      asm volatile("v_accvgpr_write_b32 %0, %1" : "=a"(ca[4*i+1]) : "v"(v.y));
      asm volatile("v_accvgpr_write_b32 %0, %1" : "=a"(ca[4*i+2]) : "v"(v.z));
      asm volatile("v_accvgpr_write_b32 %0, %1" : "=a"(ca[4*i+3]) : "v"(v.w));
    }
  }

  float dist[8];
  #pragma unroll
  for (int j = 0; j < 8; ++j) dist[j] = __builtin_huge_valf();

  __shared__ uint2 wvi[2][16];     // [step parity][wave] = {idx, valbits}

  if (tid == 0) idx_out[b * KS] = 0;
  int bi = 0;                      // wave-uniform (SGPR) winner index

  for (int step = 0; step < KS - 1; ++step) {
    const float* cp = xb + bi * 6;             // uniform -> scalar loads
    const float c0 = cp[0], c1 = cp[1], c2 = cp[2],
                c3 = cp[3], c4 = cp[4], c5 = cp[5];

    float bestv = -1.0f;                       // all dists >= 0
    int   besti = 0;
    #pragma unroll
    for (int j = 0; j < 8; ++j) {
      float xv[6];
      #pragma unroll
      for (int d = 0; d < 6; ++d)
        asm volatile("v_accvgpr_read_b32 %0, %1" : "=v"(xv[d]) : "a"(ca[6*j+d]));
      // bit-exact jnp order: sequential non-contracted sum of squares
      float t0 = xv[0] - c0; float s = t0 * t0;
      float t1 = xv[1] - c1; s = s + t1 * t1;
      float t2 = xv[2] - c2; s = s + t2 * t2;
      float t3 = xv[3] - c3; s = s + t3 * t3;
      float t4 = xv[4] - c4; s = s + t4 * t4;
      float t5 = xv[5] - c5; s = s + t5 * t5;
      float nd = fminf(dist[j], s);
      dist[j] = nd;
      if (nd > bestv) { bestv = nd; besti = tid * 8 + j; }  // ascending j: lowest idx on tie
    }

    // wave64 value-only max butterfly (6 x (swizzle + v_max))
    float wmax = bestv;
    #pragma unroll
    for (int off = 1; off < 64; off <<= 1)
      wmax = fmaxf(wmax, __shfl_xor(wmax, off, 64));
    // index: lowest lane whose bestv equals the max == first occurrence
    unsigned long long ball = __ballot(bestv == wmax);
    int wlane = (int)__builtin_ctzll(ball);
    int widx  = __builtin_amdgcn_readlane(besti, wlane);

    if (lane == 0) wvi[step & 1][wave] = make_uint2((unsigned)widx, __float_as_uint(wmax));
    __syncthreads();

    // every wave reduces the 16 per-wave results (redundant; no 2nd barrier)
    uint2 wr = wvi[step & 1][lane & 15];
    float cv = __uint_as_float(wr.y);
    #pragma unroll
    for (int off = 1; off < 16; off <<= 1)
      cv = fmaxf(cv, __shfl_xor(cv, off, 64));
    unsigned long long b2 = __ballot(__uint_as_float(wr.y) == cv);
    int cl = (int)__builtin_ctzll(b2);         // lowest wave among ties
    bi = __builtin_amdgcn_readlane((int)wr.x, cl);

    if (tid == 0) idx_out[b * KS + step + 1] = bi;
  }
}

// ===========================================================================
// Sine-MLP on the 16384 sampled points only. 64 pts/block.
// Round-11: 1024 threads (16 waves x 4 pts) instead of 512x8 -- same total
// VALU/LDS work, double the waves/SIMD (2->4) to overlap the VALU and LDS
// pipes. Accumulation order per (point,output) identical -> same numerics.
// Acts in LDS [p][c]; W tile transposed in LDS [c][COUT+1] (conflict-free).
// ===========================================================================
template<int NT, int JP, int CINP, int CINT, int COUT, int CT, bool LAST>
__device__ __forceinline__ void run_layer(const float* __restrict__ W,
                                          const float* __restrict__ bias,
                                          const float* __restrict__ in,
                                          float* __restrict__ outlds,
                                          float* __restrict__ gout,
                                          float* __restrict__ wt,
                                          int qbase, int tid) {
  constexpr int S = (COUT + 63) / 64;
  const int lane = tid & 63;
  const int wave = tid >> 6;
  const int p0   = wave * JP;

  float acc[JP][S];
  {
    float bv[S];
    #pragma unroll
    for (int s = 0; s < S; ++s) {
      int o = s * 64 + lane;
      bv[s] = (o < COUT) ? bias[o] : 0.f;
    }
    #pragma unroll
    for (int j = 0; j < JP; ++j)
      #pragma unroll
      for (int s = 0; s < S; ++s) acc[j][s] = bv[s];
  }

  for (int ct0 = 0; ct0 < CINT; ct0 += CT) {
    __syncthreads();
    #pragma unroll 1
    for (int e = tid; e < COUT * CT; e += NT) {
      int o  = e / CT;           // CT compile-time
      int cc = e % CT;
      wt[cc * (COUT + 1) + o] = W[o * CINT + ct0 + cc];
    }
    __syncthreads();
    #pragma unroll
    for (int cc0 = 0; cc0 < CT; cc0 += 4) {
      if (CT - cc0 >= 4) {
        float a[JP][4];
        #pragma unroll
        for (int j = 0; j < JP; ++j) {
          float4 t = *reinterpret_cast<const float4*>(&in[(p0 + j) * CINP + ct0 + cc0]);
          a[j][0] = t.x; a[j][1] = t.y; a[j][2] = t.z; a[j][3] = t.w;
        }
        #pragma unroll
        for (int u = 0; u < 4; ++u) {
          float wvv[S];
          #pragma unroll
          for (int s = 0; s < S; ++s)
            wvv[s] = wt[(cc0 + u) * (COUT + 1) + s * 64 + lane];
          #pragma unroll
          for (int j = 0; j < JP; ++j)
            #pragma unroll
            for (int s = 0; s < S; ++s)
              acc[j][s] = fmaf(a[j][u], wvv[s], acc[j][s]);
        }
      } else {   // remainder of 2 (layer 1, CT=6)
        float a[JP][2];
        #pragma unroll
        for (int j = 0; j < JP; ++j) {
          float2 t = *reinterpret_cast<const float2*>(&in[(p0 + j) * CINP + ct0 + cc0]);
          a[j][0] = t.x; a[j][1] = t.y;
        }
        #pragma unroll
        for (int u = 0; u < 2; ++u) {
          float wvv[S];
          #pragma unroll
          for (int s = 0; s < S; ++s)
            wvv[s] = wt[(cc0 + u) * (COUT + 1) + s * 64 + lane];
          #pragma unroll
          for (int j = 0; j < JP; ++j)
            #pragma unroll
            for (int s = 0; s < S; ++s)
              acc[j][s] = fmaf(a[j][u], wvv[s], acc[j][s]);
        }
      }
    }
  }
  #pragma unroll
  for (int j = 0; j < JP; ++j) {
    #pragma unroll
    for (int s = 0; s < S; ++s) {
      int o = s * 64 + lane;
      if (o < COUT) {
        float r = sinf(acc[j][s]);
        if (LAST) gout[(size_t)(qbase + p0 + j) * 512 + o] = r;
        else      outlds[(p0 + j) * COUT + o] = r;
      }
    }
  }
}

__global__ __launch_bounds__(1024, 4) void mlp_kernel(
    const float* __restrict__ x, const int* __restrict__ sidx,
    const float* __restrict__ W1, const float* __restrict__ B1,
    const float* __restrict__ W2, const float* __restrict__ B2,
    const float* __restrict__ W3, const float* __restrict__ B3,
    const float* __restrict__ W4, const float* __restrict__ B4,
    const float* __restrict__ W5, const float* __restrict__ B5,
    const float* __restrict__ W6, const float* __restrict__ B6,
    float* __restrict__ out) {
  __shared__ float A[64 * 128];
  __shared__ float Bb[64 * 256];
  __shared__ float wt[16 * 513];
  const int tid   = threadIdx.x;
  const int qbase = blockIdx.x * 64;

  if (tid < 64) {              // gather sampled points, stride-8 rows
    int q  = qbase + tid;
    int bb = q >> 10;
    int id = sidx[q];
    const float* xr = x + ((size_t)bb * NPTS + id) * 6;
    #pragma unroll
    for (int d = 0; d < 6; ++d) A[tid * 8 + d] = xr[d];
  }
  // (first barrier inside run_layer covers the gather)
  run_layer<1024, 4, 8,   6,  32,  6, false>(W1, B1, A,  Bb, nullptr, wt, qbase, tid);
  run_layer<1024, 4, 32,  32,  64, 16, false>(W2, B2, Bb, A,  nullptr, wt, qbase, tid);
  run_layer<1024, 4, 64,  64,  64, 16, false>(W3, B3, A,  Bb, nullptr, wt, qbase, tid);
  run_layer<1024, 4, 64,  64, 128, 16, false>(W4, B4, Bb, A,  nullptr, wt, qbase, tid);
  run_layer<1024, 4, 128, 128, 256, 16, false>(W5, B5, A,  Bb, nullptr, wt, qbase, tid);
  run_layer<1024, 4, 256, 256, 512, 16, true >(W6, B6, Bb, nullptr, out, wt, qbase, tid);
}

extern "C" void kernel_launch(void* const* d_in, const int* in_sizes, int n_in,
                              void* d_out, int out_size, void* d_ws, size_t ws_size,
                              hipStream_t stream) {
  const float* x  = (const float*)d_in[0];
  const float* W1 = (const float*)d_in[1];  const float* B1 = (const float*)d_in[2];
  const float* W2 = (const float*)d_in[3];  const float* B2 = (const float*)d_in[4];
  const float* W3 = (const float*)d_in[5];  const float* B3 = (const float*)d_in[6];
  const float* W4 = (const float*)d_in[7];  const float* B4 = (const float*)d_in[8];
  const float* W5 = (const float*)d_in[9];  const float* B5 = (const float*)d_in[10];
  const float* W6 = (const float*)d_in[11]; const float* B6 = (const float*)d_in[12];
  int*   idxbuf = (int*)d_ws;                              // 64 KB scratch
  float* out    = (float*)d_out;                           // [16,1024,512] fp32

  fps_kernel<<<NB, 1024, 0, stream>>>(x, idxbuf);
  mlp_kernel<<<256, 1024, 0, stream>>>(x, idxbuf,
                                       W1, B1, W2, B2, W3, B3,
                                       W4, B4, W5, B5, W6, B6, out);
}